// Round 1
// baseline (2551.204 us; speedup 1.0000x reference)
//
#include <hip/hip_runtime.h>
#include <math.h>

#define TT 516
#define BB 16
#define DD 512
#define LL 512
#define NN 512
#define HH 8
#define DHD 64
#define DFF 2048
#define PP 336
#define MM 512
#define KNN 10
#define BT (BB*TT)      /* 8256 */
#define PN (PP*NN)      /* 172032 */

__device__ __forceinline__ float gelu_tanh(float x){
    float x3 = x*x*x;
    return 0.5f*x*(1.0f + tanhf(0.7978845608028654f*(x + 0.044715f*x3)));
}

// ---------------------------------------------------------------------------
// Generic fp32 tiled GEMM: C[M,N] = A[M,K] @ B[K,N] + bias, 64x64 tile, BK=32
// ALOAD: 0 = flat row-major A, 1 = embed gather from x_enc/x_mark (transposed)
// EPI:   0 = plain store, 1 = gelu store, 2 = pred transpose-store
// ---------------------------------------------------------------------------
template<int ALOAD, int EPI>
__global__ __launch_bounds__(256)
void gemm_k(const float* __restrict__ A, const float* __restrict__ Bm,
            const float* __restrict__ bias, float* __restrict__ C,
            int Msz, int Nsz, int Ksz,
            const float* __restrict__ x_enc, const float* __restrict__ x_mark)
{
    __shared__ float AT[32][68];   // transposed A tile: AT[k][r]
    __shared__ float Bs[32][68];   // natural B tile:    Bs[k][c]
    const int tid = threadIdx.x;
    const int ty  = tid >> 4, tx = tid & 15;
    const int ty4 = ty*4, tx4 = tx*4;
    const int c0  = blockIdx.x * 64;
    const int rt0 = blockIdx.y * 64;

    float acc[4][4];
#pragma unroll
    for (int i=0;i<4;i++)
#pragma unroll
        for (int j=0;j<4;j++) acc[i][j] = 0.0f;

    for (int kt = 0; kt < Ksz; kt += 32){
        __syncthreads();
        // ---- stage A (transposed into AT[k][r]) ----
        if (ALOAD == 0){
            int r  = tid >> 2;
            int kc = (tid & 3) * 8;
            const float* ap = A + (size_t)(rt0 + r)*Ksz + kt + kc;
            float4 a0 = *(const float4*)ap;
            float4 a1 = *(const float4*)(ap + 4);
            AT[kc+0][r] = a0.x; AT[kc+1][r] = a0.y; AT[kc+2][r] = a0.z; AT[kc+3][r] = a0.w;
            AT[kc+4][r] = a1.x; AT[kc+5][r] = a1.y; AT[kc+6][r] = a1.z; AT[kc+7][r] = a1.w;
        } else {
            int kk = tid >> 3;          // 0..31
            int rc = (tid & 7) * 8;     // 0..56
            int l  = kt + kk;
            float vbuf[8];
#pragma unroll
            for (int c=0;c<8;c++){
                int rg = rt0 + rc + c;
                int b  = rg / TT;
                int t  = rg - b*TT;
                float val;
                if (t < NN) val = x_enc[((size_t)b*LL + l)*NN + t];
                else        val = x_mark[((size_t)b*LL + l)*4 + (t - NN)];
                vbuf[c] = val;
            }
            float4 w0, w1;
            w0.x=vbuf[0]; w0.y=vbuf[1]; w0.z=vbuf[2]; w0.w=vbuf[3];
            w1.x=vbuf[4]; w1.y=vbuf[5]; w1.z=vbuf[6]; w1.w=vbuf[7];
            *(float4*)&AT[kk][rc]   = w0;
            *(float4*)&AT[kk][rc+4] = w1;
        }
        // ---- stage B ----
        {
            int kk = tid >> 3;          // 0..31
            int cc = (tid & 7) * 8;     // 0..56
            int cg = c0 + cc;
            const float* bp = Bm + (size_t)(kt + kk)*Nsz + cg;
            float4 v0, v1;
            if (cg + 7 < Nsz){
                v0 = *(const float4*)bp;
                v1 = *(const float4*)(bp + 4);
            } else {
                float tmp[8];
#pragma unroll
                for (int c=0;c<8;c++) tmp[c] = (cg + c < Nsz) ? bp[c] : 0.0f;
                v0.x=tmp[0]; v0.y=tmp[1]; v0.z=tmp[2]; v0.w=tmp[3];
                v1.x=tmp[4]; v1.y=tmp[5]; v1.z=tmp[6]; v1.w=tmp[7];
            }
            *(float4*)&Bs[kk][cc]   = v0;
            *(float4*)&Bs[kk][cc+4] = v1;
        }
        __syncthreads();
        // ---- compute ----
#pragma unroll
        for (int k2=0;k2<32;k2++){
            float4 av = *(const float4*)&AT[k2][ty4];
            float4 bv = *(const float4*)&Bs[k2][tx4];
            float a[4] = {av.x, av.y, av.z, av.w};
            float b[4] = {bv.x, bv.y, bv.z, bv.w};
#pragma unroll
            for (int i=0;i<4;i++)
#pragma unroll
                for (int j=0;j<4;j++)
                    acc[i][j] = fmaf(a[i], b[j], acc[i][j]);
        }
    }

    // ---- epilogue ----
    if (EPI == 0 || EPI == 1){
        int cg = c0 + tx4;
#pragma unroll
        for (int i=0;i<4;i++){
            int rg = rt0 + ty4 + i;
            float4 ov;
            float o0 = acc[i][0] + bias[cg+0];
            float o1 = acc[i][1] + bias[cg+1];
            float o2 = acc[i][2] + bias[cg+2];
            float o3 = acc[i][3] + bias[cg+3];
            if (EPI == 1){ o0=gelu_tanh(o0); o1=gelu_tanh(o1); o2=gelu_tanh(o2); o3=gelu_tanh(o3); }
            ov.x=o0; ov.y=o1; ov.z=o2; ov.w=o3;
            if (cg + 3 < Nsz){
                *(float4*)(C + (size_t)rg*Nsz + cg) = ov;
            } else {
                if (cg+0 < Nsz) C[(size_t)rg*Nsz + cg+0] = o0;
                if (cg+1 < Nsz) C[(size_t)rg*Nsz + cg+1] = o1;
                if (cg+2 < Nsz) C[(size_t)rg*Nsz + cg+2] = o2;
                if (cg+3 < Nsz) C[(size_t)rg*Nsz + cg+3] = o3;
            }
        }
    } else {
        // pred store: row rg -> (b,t), col = horizon p; write pred[(b*PP+p)*NN + t], only t<NN
#pragma unroll
        for (int i=0;i<4;i++){
            int rg = rt0 + ty4 + i;
            int b  = rg / TT;
            int t  = rg - b*TT;
            if (t < NN){
#pragma unroll
                for (int j=0;j<4;j++){
                    int p = c0 + tx4 + j;
                    if (p < PP)
                        C[((size_t)b*PP + p)*NN + t] = acc[i][j] + bias[p];
                }
            }
        }
    }
}

// ---------------------------------------------------------------------------
// Flash-style fp32 attention. q,k,v: [B*T, D] with head-major cols (h*64+d).
// Block = one (b, h, 64-row t-tile). Online softmax over 9 s-tiles of 64.
// ---------------------------------------------------------------------------
__global__ __launch_bounds__(256)
void attn_k(const float* __restrict__ q, const float* __restrict__ k,
            const float* __restrict__ v, float* __restrict__ o)
{
    const int tt = blockIdx.x;   // 0..8
    const int h  = blockIdx.y;   // 0..7
    const int b  = blockIdx.z;   // 0..15
    const int t0 = tt * 64;
    const int tid = threadIdx.x;
    const int ty = tid >> 4, tx = tid & 15;
    const int ty4 = ty*4, tx4 = tx*4;

    __shared__ float QT[64][68];  // QT[d][r]
    __shared__ float KT[64][68];  // KT[d][s]
    __shared__ float Vs[64][68];  // Vs[s][d]
    __shared__ float PT[64][68];  // PT[s][r]

    // stage Q transposed
    {
        int r  = tid >> 2;
        int dc = (tid & 3) * 16;
        int t  = t0 + r;
#pragma unroll
        for (int c=0;c<4;c++){
            float4 val;
            if (t < TT){
                val = *(const float4*)(q + ((size_t)(b*TT + t))*DD + h*DHD + dc + 4*c);
            } else { val.x=val.y=val.z=val.w=0.0f; }
            QT[dc+4*c+0][r] = val.x; QT[dc+4*c+1][r] = val.y;
            QT[dc+4*c+2][r] = val.z; QT[dc+4*c+3][r] = val.w;
        }
    }

    float accO[4][4];
    float mrow[4], lrow[4];
#pragma unroll
    for (int i=0;i<4;i++){
        mrow[i] = -1e30f; lrow[i] = 0.0f;
#pragma unroll
        for (int j=0;j<4;j++) accO[i][j] = 0.0f;
    }
    const float scale = 0.125f;

    for (int st=0; st<9; st++){
        int s0 = st*64;
        __syncthreads();
        // stage K (transposed) and V (natural)
        {
            int r  = tid >> 2;
            int dc = (tid & 3) * 16;
            int s  = s0 + r;
#pragma unroll
            for (int c=0;c<4;c++){
                float4 kv, vv;
                if (s < TT){
                    kv = *(const float4*)(k + ((size_t)(b*TT + s))*DD + h*DHD + dc + 4*c);
                    vv = *(const float4*)(v + ((size_t)(b*TT + s))*DD + h*DHD + dc + 4*c);
                } else {
                    kv.x=kv.y=kv.z=kv.w=0.0f; vv.x=vv.y=vv.z=vv.w=0.0f;
                }
                KT[dc+4*c+0][r] = kv.x; KT[dc+4*c+1][r] = kv.y;
                KT[dc+4*c+2][r] = kv.z; KT[dc+4*c+3][r] = kv.w;
                *(float4*)&Vs[r][dc+4*c] = vv;
            }
        }
        __syncthreads();
        // S = Q K^T for this tile
        float sacc[4][4];
#pragma unroll
        for (int i=0;i<4;i++)
#pragma unroll
            for (int j=0;j<4;j++) sacc[i][j] = 0.0f;
#pragma unroll 8
        for (int d=0; d<64; d++){
            float4 av = *(const float4*)&QT[d][ty4];
            float4 bv = *(const float4*)&KT[d][tx4];
            float a[4] = {av.x, av.y, av.z, av.w};
            float bb[4] = {bv.x, bv.y, bv.z, bv.w};
#pragma unroll
            for (int i=0;i<4;i++)
#pragma unroll
                for (int j=0;j<4;j++)
                    sacc[i][j] = fmaf(a[i], bb[j], sacc[i][j]);
        }
        // online softmax update
        float p[4][4];
#pragma unroll
        for (int i=0;i<4;i++){
            float mx = -1e30f;
#pragma unroll
            for (int j=0;j<4;j++){
                float sv = sacc[i][j]*scale;
                if (s0 + tx4 + j >= TT) sv = -1e30f;
                p[i][j] = sv;
                mx = fmaxf(mx, sv);
            }
#pragma unroll
            for (int msk=1; msk<16; msk<<=1) mx = fmaxf(mx, __shfl_xor(mx, msk));
            float mnew  = fmaxf(mrow[i], mx);
            float alpha = __expf(mrow[i] - mnew);
            mrow[i] = mnew;
            float rs = 0.0f;
#pragma unroll
            for (int j=0;j<4;j++){
                float e = __expf(p[i][j] - mnew);
                p[i][j] = e;
                rs += e;
            }
#pragma unroll
            for (int msk=1; msk<16; msk<<=1) rs += __shfl_xor(rs, msk);
            lrow[i] = lrow[i]*alpha + rs;
#pragma unroll
            for (int j=0;j<4;j++) accO[i][j] *= alpha;
        }
        // write P transposed
#pragma unroll
        for (int j=0;j<4;j++)
#pragma unroll
            for (int i=0;i<4;i++)
                PT[tx4+j][ty4+i] = p[i][j];
        __syncthreads();
        // O += P V
#pragma unroll 8
        for (int s=0; s<64; s++){
            float4 pa = *(const float4*)&PT[s][ty4];
            float4 vb = *(const float4*)&Vs[s][tx4];
            float a[4] = {pa.x, pa.y, pa.z, pa.w};
            float bb[4] = {vb.x, vb.y, vb.z, vb.w};
#pragma unroll
            for (int i=0;i<4;i++)
#pragma unroll
                for (int j=0;j<4;j++)
                    accO[i][j] = fmaf(a[i], bb[j], accO[i][j]);
        }
    }
    // store
#pragma unroll
    for (int i=0;i<4;i++){
        int t = t0 + ty4 + i;
        if (t < TT){
            float inv = 1.0f/lrow[i];
            float4 ov;
            ov.x = accO[i][0]*inv; ov.y = accO[i][1]*inv;
            ov.z = accO[i][2]*inv; ov.w = accO[i][3]*inv;
            *(float4*)(o + ((size_t)(b*TT + t))*DD + h*DHD + tx4) = ov;
        }
    }
}

// ---------------------------------------------------------------------------
// Residual + LayerNorm over D=512: dst = LN(src + res) * w + b (res nullable)
// ---------------------------------------------------------------------------
__global__ __launch_bounds__(256)
void ln_k(const float* __restrict__ src, const float* __restrict__ res,
          const float* __restrict__ w, const float* __restrict__ bia,
          float* __restrict__ dst)
{
    const int r = blockIdx.x;
    const int tid = threadIdx.x;
    const float* sp = src + (size_t)r*DD;
    float x0 = sp[tid], x1 = sp[tid + 256];
    if (res){
        x0 += res[(size_t)r*DD + tid];
        x1 += res[(size_t)r*DD + tid + 256];
    }
    float s  = x0 + x1;
    float sq = x0*x0 + x1*x1;
#pragma unroll
    for (int msk=1; msk<64; msk<<=1){
        s  += __shfl_xor(s,  msk);
        sq += __shfl_xor(sq, msk);
    }
    __shared__ float sm[8];
    int wv = tid >> 6, ln = tid & 63;
    if (ln == 0){ sm[wv] = s; sm[wv+4] = sq; }
    __syncthreads();
    s  = sm[0]+sm[1]+sm[2]+sm[3];
    sq = sm[4]+sm[5]+sm[6]+sm[7];
    float mu  = s * (1.0f/512.0f);
    float var = sq * (1.0f/512.0f) - mu*mu;
    float rsd = rsqrtf(var + 1e-5f);
    dst[(size_t)r*DD + tid]       = (x0 - mu)*rsd*w[tid]       + bia[tid];
    dst[(size_t)r*DD + tid + 256] = (x1 - mu)*rsd*w[tid + 256] + bia[tid + 256];
}

// ---------------------------------------------------------------------------
// sims split-K partials: dot of every bank row (528 = 512 bank + 16 pred)
// against all 16 pred rows + bank-row norm^2, over K-chunk of 10752 elems.
// grid (33 j-tiles of 16, 16 k-chunks), block 256 = 16j x 16q
// ---------------------------------------------------------------------------
__global__ __launch_bounds__(256)
void simspart_k(const float* __restrict__ pred, const float* __restrict__ bank,
                float* __restrict__ dotp, float* __restrict__ nrmp)
{
    const int jt = blockIdx.x, kt = blockIdx.y;
    const int tid = threadIdx.x;
    const int jj = tid >> 4, qq = tid & 15;
    const int j  = jt*16 + jj;
    __shared__ float BS[16][68], PS[16][68];
    float dot = 0.0f, nr = 0.0f;
    const int e0base = kt * 10752;
    for (int eo=0; eo<10752; eo+=64){
        __syncthreads();
        {
            int rr = tid >> 4;
            int e4 = (tid & 15) * 4;
            int jr = jt*16 + rr;
            const float* bp = (jr < MM) ? (bank + (size_t)jr*PN)
                                        : (pred + (size_t)(jr - MM)*PN);
            *(float4*)&BS[rr][e4] = *(const float4*)(bp + e0base + eo + e4);
            *(float4*)&PS[rr][e4] = *(const float4*)(pred + (size_t)rr*PN + e0base + eo + e4);
        }
        __syncthreads();
#pragma unroll 16
        for (int e=0;e<64;e++){
            float bv = BS[jj][e];
            float pv = PS[qq][e];
            dot = fmaf(bv, pv, dot);
            nr  = fmaf(bv, bv, nr);
        }
    }
    dotp[((size_t)kt*528 + j)*16 + qq] = dot;
    if (qq == 0) nrmp[kt*528 + j] = nr;
}

__global__ void norms_k(const float* __restrict__ nrmp, float* __restrict__ invn){
    int j = blockIdx.x*blockDim.x + threadIdx.x;
    if (j < 528){
        float s = 0.0f;
        for (int kt=0; kt<16; kt++) s += nrmp[kt*528 + j];
        invn[j] = 1.0f/(sqrtf(s) + 1e-8f);
    }
}

__global__ void simsfin_k(const float* __restrict__ dotp, const float* __restrict__ invn,
                          float* __restrict__ sims){
    int fid = blockIdx.x*256 + threadIdx.x;   // < 8448
    int j = fid >> 4, q = fid & 15;
    float s = 0.0f;
    for (int kt=0; kt<16; kt++) s += dotp[((size_t)kt*528 + j)*16 + q];
    sims[q*528 + j] = s * invn[j] * invn[MM + q];
}

// exact stable top-K (ties -> lower index), one wave per query
__global__ __launch_bounds__(64)
void topk_k(const float* __restrict__ sims, int* __restrict__ idx){
    const int q = blockIdx.x;
    const int lane = threadIdx.x;
    __shared__ float vals[528];
    for (int j=lane; j<528; j+=64) vals[j] = sims[q*528 + j];
    __syncthreads();
    for (int kk=0; kk<KNN; kk++){
        float bv = -3.0e38f; int bi = 1<<30;
        for (int j=lane; j<528; j+=64){
            float v2 = vals[j];
            if (v2 > bv || (v2 == bv && j < bi)){ bv = v2; bi = j; }
        }
#pragma unroll
        for (int msk=1; msk<64; msk<<=1){
            float ov = __shfl_xor(bv, msk);
            int   oi = __shfl_xor(bi, msk);
            if (ov > bv || (ov == bv && oi < bi)){ bv = ov; bi = oi; }
        }
        if (lane == 0){
            idx[q*KNN + kk] = bi;
            vals[bi] = -3.0e38f;
        }
        __syncthreads();
    }
}

__global__ __launch_bounds__(256)
void fuse_k(const float* __restrict__ pred, const float* __restrict__ bank,
            const int* __restrict__ idx, float* __restrict__ out){
    int u = blockIdx.x*256 + threadIdx.x;   // float4 index, < 688128
    int b = u / (PN/4);
    int e = (u - b*(PN/4)) * 4;
    int id[KNN];
#pragma unroll
    for (int k2=0;k2<KNN;k2++) id[k2] = idx[b*KNN + k2];
    float4 pv = *(const float4*)(pred + (size_t)b*PN + e);
    float ax = 0.5f*pv.x, ay = 0.5f*pv.y, az = 0.5f*pv.z, aw = 0.5f*pv.w;
#pragma unroll
    for (int k2=0;k2<KNN;k2++){
        const float* rp = (id[k2] < MM) ? (bank + (size_t)id[k2]*PN)
                                        : (pred + (size_t)(id[k2]-MM)*PN);
        float4 rv = *(const float4*)(rp + e);
        ax = fmaf(0.05f, rv.x, ax); ay = fmaf(0.05f, rv.y, ay);
        az = fmaf(0.05f, rv.z, az); aw = fmaf(0.05f, rv.w, aw);
    }
    float4 ov; ov.x=ax; ov.y=ay; ov.z=az; ov.w=aw;
    *(float4*)(out + (size_t)b*PN + e) = ov;
}

// ---------------------------------------------------------------------------
extern "C" void kernel_launch(void* const* d_in, const int* in_sizes, int n_in,
                              void* d_out, int out_size, void* d_ws, size_t ws_size,
                              hipStream_t stream)
{
    (void)in_sizes; (void)n_in; (void)out_size; (void)ws_size;
    const float* x_enc  = (const float*)d_in[0];
    const float* x_mark = (const float*)d_in[1];
    const float* W_emb  = (const float*)d_in[4];
    const float* b_emb  = (const float*)d_in[5];
    const float* Wq  = (const float*)d_in[6];
    const float* Wk  = (const float*)d_in[7];
    const float* Wv  = (const float*)d_in[8];
    const float* Wo  = (const float*)d_in[9];
    const float* bq  = (const float*)d_in[10];
    const float* bk  = (const float*)d_in[11];
    const float* bv_ = (const float*)d_in[12];
    const float* bo  = (const float*)d_in[13];
    const float* ln1w = (const float*)d_in[14];
    const float* ln1b = (const float*)d_in[15];
    const float* ln2w = (const float*)d_in[16];
    const float* ln2b = (const float*)d_in[17];
    const float* Wff1 = (const float*)d_in[18];
    const float* bff1 = (const float*)d_in[19];
    const float* Wff2 = (const float*)d_in[20];
    const float* bff2 = (const float*)d_in[21];
    const float* lnfw = (const float*)d_in[22];
    const float* lnfb = (const float*)d_in[23];
    const float* Wproj = (const float*)d_in[24];
    const float* bproj = (const float*)d_in[25];
    const float* bank  = (const float*)d_in[26];
    float* out = (float*)d_out;
    float* ws  = (float*)d_ws;

    float* h    = ws;
    float* qb   = h   + (size_t)BT*DD;
    float* kb   = qb  + (size_t)BT*DD;
    float* vb   = kb  + (size_t)BT*DD;
    float* t1   = vb  + (size_t)BT*DD;
    float* mid  = t1  + (size_t)BT*DD;
    float* pred = mid + (size_t)BT*DFF;
    float* dotp = pred + (size_t)BB*PN;
    float* nrmp = dotp + (size_t)16*528*16;
    float* invn = nrmp + 528*16;
    float* sims = invn + 528;
    int*   idxp = (int*)(sims + 16*528);

    dim3 blk(256);

    // 1) inverted embedding: h = tok @ W_emb + b_emb  (tok gathered on the fly)
    gemm_k<1,0><<<dim3(DD/64, BT/64), blk, 0, stream>>>(
        nullptr, W_emb, b_emb, h, BT, DD, LL, x_enc, x_mark);

    for (int i=0;i<2;i++){
        const float* wq = Wq + (size_t)i*DD*DD;
        const float* wk = Wk + (size_t)i*DD*DD;
        const float* wv = Wv + (size_t)i*DD*DD;
        const float* wo = Wo + (size_t)i*DD*DD;
        gemm_k<0,0><<<dim3(DD/64, BT/64), blk, 0, stream>>>(
            h, wq, bq + i*DD, qb, BT, DD, DD, nullptr, nullptr);
        gemm_k<0,0><<<dim3(DD/64, BT/64), blk, 0, stream>>>(
            h, wk, bk + i*DD, kb, BT, DD, DD, nullptr, nullptr);
        gemm_k<0,0><<<dim3(DD/64, BT/64), blk, 0, stream>>>(
            h, wv, bv_ + i*DD, vb, BT, DD, DD, nullptr, nullptr);
        attn_k<<<dim3(9, HH, BB), blk, 0, stream>>>(qb, kb, vb, t1);
        gemm_k<0,0><<<dim3(DD/64, BT/64), blk, 0, stream>>>(
            t1, wo, bo + i*DD, qb, BT, DD, DD, nullptr, nullptr);
        ln_k<<<BT, blk, 0, stream>>>(h, qb, ln1w + i*DD, ln1b + i*DD, h);
        gemm_k<0,1><<<dim3(DFF/64, BT/64), blk, 0, stream>>>(
            h, Wff1 + (size_t)i*DD*DFF, bff1 + i*DFF, mid, BT, DFF, DD, nullptr, nullptr);
        gemm_k<0,0><<<dim3(DD/64, BT/64), blk, 0, stream>>>(
            mid, Wff2 + (size_t)i*DFF*DD, bff2 + i*DD, qb, BT, DD, DFF, nullptr, nullptr);
        ln_k<<<BT, blk, 0, stream>>>(h, qb, ln2w + i*DD, ln2b + i*DD, h);
    }

    // 3) final LN
    ln_k<<<BT, blk, 0, stream>>>(h, nullptr, lnfw, lnfb, h);

    // 4) projection to horizon with transpose-store into pred[B,P,N]
    gemm_k<0,2><<<dim3(6, BT/64), blk, 0, stream>>>(
        h, Wproj, bproj, pred, BT, PP, DD, nullptr, nullptr);

    // 5) memory-bank cosine sims (deterministic split-K, no atomics)
    simspart_k<<<dim3(33,16), blk, 0, stream>>>(pred, bank, dotp, nrmp);
    norms_k<<<dim3(3), blk, 0, stream>>>(nrmp, invn);
    simsfin_k<<<dim3(33), blk, 0, stream>>>(dotp, invn, sims);

    // 6) top-K and fusion
    topk_k<<<dim3(BB), dim3(64), 0, stream>>>(sims, idxp);
    fuse_k<<<dim3((BB*PN/4)/256), blk, 0, stream>>>(pred, bank, idxp, out);
}

// Round 2
// 1493.855 us; speedup vs baseline: 1.7078x; 1.7078x over previous
//
#include <hip/hip_runtime.h>
#include <stdint.h>
#include <math.h>

#define TT 516
#define BB 16
#define DD 512
#define LL 512
#define NN 512
#define HH 8
#define DHD 64
#define DFFN 2048
#define PP 336
#define MM 512
#define KNN 10
#define BT (BB*TT)      /* 8256 */
#define PN (PP*NN)      /* 172032 */

using f32x4  = __attribute__((ext_vector_type(4))) float;
using bf16x8 = __attribute__((ext_vector_type(8))) __bf16;
using u16x8  = __attribute__((ext_vector_type(8))) unsigned short;

__device__ __forceinline__ float gelu_tanh(float x){
    float x3 = x*x*x;
    return 0.5f*x*(1.0f + tanhf(0.7978845608028654f*(x + 0.044715f*x3)));
}

__device__ __forceinline__ uint16_t f2bf(float x){
    uint32_t u = __builtin_bit_cast(uint32_t, x);
    uint32_t r = (u + 0x7FFFu + ((u >> 16) & 1u)) >> 16;
    return (uint16_t)r;
}

__device__ __forceinline__ void split_bf(float x, uint16_t& hi, uint16_t& lo){
    uint32_t u  = __builtin_bit_cast(uint32_t, x);
    uint32_t hr = (u + 0x7FFFu + ((u >> 16) & 1u)) & 0xFFFF0000u;
    float hf = __builtin_bit_cast(float, hr);
    hi = (uint16_t)(hr >> 16);
    lo = f2bf(x - hf);
}

__device__ __forceinline__ void gl16(const uint16_t* g, uint16_t* l){
    __builtin_amdgcn_global_load_lds(
        (const __attribute__((address_space(1))) unsigned int*)(const void*)g,
        (__attribute__((address_space(3))) unsigned int*)(void*)l, 16, 0, 0);
}

#define EPI_F32   1
#define EPI_BF16  2
#define EPI_GELU  4
#define EPI_PREDT 8
#define EPI_QKV   16

// ---------------------------------------------------------------------------
// Split-bf16 MFMA GEMM: C = A*B^T(+bias). A planes [M][K] bf16 hi/lo,
// B planes [N][K] bf16 hi/lo (pre-transposed weights). Tile 128xBN, BK=32.
// acc += Ahi*Bhi + Ahi*Blo + Alo*Bhi  (fp32 accumulate) -> ~fp32 precision.
// ---------------------------------------------------------------------------
template<int BN, int FLAGS>
__global__ __launch_bounds__(256)
void bgemm(const uint16_t* __restrict__ Ah, const uint16_t* __restrict__ Al,
           const uint16_t* __restrict__ Bh, const uint16_t* __restrict__ Bl,
           const float* __restrict__ bias, float* __restrict__ Cf,
           uint16_t* __restrict__ Cbh, uint16_t* __restrict__ Cbl,
           int Msz, int Nsz, int Ksz)
{
    constexpr int FN = BN/32;             // frags per wave in N (BN=128->4, 64->2)
    __shared__ uint16_t As0[4096], As1[4096];
    __shared__ uint16_t Bs0[BN*32], Bs1[BN*32];

    const int tid  = threadIdx.x;
    const int lane = tid & 63;
    const int wu   = __builtin_amdgcn_readfirstlane(tid >> 6);
    const int wm   = wu >> 1, wn = wu & 1;
    const int m0   = blockIdx.y * 128;
    const int n0   = blockIdx.x * BN;

    // staging source addresses (per-lane, XOR-pre-swizzled k-chunk)
    const int r0c = tid >> 2;
    const int cc  = tid & 3;
    const int sw  = (r0c ^ (r0c >> 2)) & 3;
    const int csw = (cc ^ sw) * 8;
    int rA0 = m0 + r0c;      if (rA0 > Msz-1) rA0 = Msz-1;
    int rA1 = m0 + r0c + 64; if (rA1 > Msz-1) rA1 = Msz-1;
    int rB0 = n0 + r0c;      if (rB0 > Nsz-1) rB0 = Nsz-1;
    int rB1 = n0 + r0c + 64; if (rB1 > Nsz-1) rB1 = Nsz-1;
    const uint16_t* pAh0 = Ah + (size_t)rA0*Ksz + csw;
    const uint16_t* pAh1 = Ah + (size_t)rA1*Ksz + csw;
    const uint16_t* pAl0 = Al + (size_t)rA0*Ksz + csw;
    const uint16_t* pAl1 = Al + (size_t)rA1*Ksz + csw;
    const uint16_t* pBh0 = Bh + (size_t)rB0*Ksz + csw;
    const uint16_t* pBh1 = Bh + (size_t)rB1*Ksz + csw;
    const uint16_t* pBl0 = Bl + (size_t)rB0*Ksz + csw;
    const uint16_t* pBl1 = Bl + (size_t)rB1*Ksz + csw;

    f32x4 acc[4][FN];
#pragma unroll
    for (int i=0;i<4;i++)
#pragma unroll
        for (int j=0;j<FN;j++) acc[i][j] = (f32x4){0.f,0.f,0.f,0.f};

    const int lc16  = lane & 15;
    const int slot8 = (((lane>>4) ^ (lane&3) ^ ((lane>>2)&3))) * 8;
    const int rAf   = (wm*64 + lc16) * 32 + slot8;
    const int rBf   = (wn*(BN/2) + lc16) * 32 + slot8;

    for (int kt = 0; kt < Ksz; kt += 32){
        gl16(pAh0 + kt, &As0[wu*512]);
        gl16(pAh1 + kt, &As0[2048 + wu*512]);
        gl16(pAl0 + kt, &As1[wu*512]);
        gl16(pAl1 + kt, &As1[2048 + wu*512]);
        if (BN == 128){
            gl16(pBh0 + kt, &Bs0[wu*512]);
            gl16(pBh1 + kt, &Bs0[2048 + wu*512]);
            gl16(pBl0 + kt, &Bs1[wu*512]);
            gl16(pBl1 + kt, &Bs1[2048 + wu*512]);
        } else {
            gl16(pBh0 + kt, &Bs0[wu*512]);
            gl16(pBl0 + kt, &Bs1[wu*512]);
        }
        __syncthreads();

        bf16x8 ah[4], al[4], bh[FN], bl[FN];
#pragma unroll
        for (int fm=0; fm<4; fm++){
            ah[fm] = __builtin_bit_cast(bf16x8, *(const u16x8*)&As0[rAf + fm*512]);
            al[fm] = __builtin_bit_cast(bf16x8, *(const u16x8*)&As1[rAf + fm*512]);
        }
#pragma unroll
        for (int fn=0; fn<FN; fn++){
            bh[fn] = __builtin_bit_cast(bf16x8, *(const u16x8*)&Bs0[rBf + fn*512]);
            bl[fn] = __builtin_bit_cast(bf16x8, *(const u16x8*)&Bs1[rBf + fn*512]);
        }
#pragma unroll
        for (int fm=0; fm<4; fm++)
#pragma unroll
            for (int fn=0; fn<FN; fn++){
                acc[fm][fn] = __builtin_amdgcn_mfma_f32_16x16x32_bf16(ah[fm], bh[fn], acc[fm][fn], 0,0,0);
                acc[fm][fn] = __builtin_amdgcn_mfma_f32_16x16x32_bf16(ah[fm], bl[fn], acc[fm][fn], 0,0,0);
                acc[fm][fn] = __builtin_amdgcn_mfma_f32_16x16x32_bf16(al[fm], bh[fn], acc[fm][fn], 0,0,0);
            }
        __syncthreads();
    }

    // ---- epilogue ----
    const int lr4 = (lane >> 4) * 4;
#pragma unroll
    for (int fm=0; fm<4; fm++){
        const int rbase = m0 + wm*64 + fm*16 + lr4;
#pragma unroll
        for (int fn=0; fn<FN; fn++){
            const int col = n0 + wn*(BN/2) + fn*16 + lc16;
            f32x4 v = acc[fm][fn];
            if (FLAGS & EPI_PREDT){
#pragma unroll
                for (int r=0;r<4;r++){
                    int row = rbase + r;
                    if (row < Msz && col < PP){
                        int b = row / TT, t = row - b*TT;
                        if (t < NN)
                            Cf[((size_t)b*PP + col)*NN + t] = v[r] + bias[col];
                    }
                }
            } else {
                const float bcol = bias[col];
#pragma unroll
                for (int r=0;r<4;r++){
                    int row = rbase + r;
                    if (row < Msz){
                        float x = v[r] + bcol;
                        if (FLAGS & EPI_GELU) x = gelu_tanh(x);
                        if (FLAGS & EPI_QKV){
                            Cf[(size_t)(col>>9)*((size_t)BT*512) + (size_t)row*512 + (col&511)] = x;
                        } else {
                            if (FLAGS & EPI_F32) Cf[(size_t)row*Nsz + col] = x;
                        }
                        if (FLAGS & EPI_BF16){
                            uint16_t hi, lo; split_bf(x, hi, lo);
                            Cbh[(size_t)row*Nsz + col] = hi;
                            Cbl[(size_t)row*Nsz + col] = lo;
                        }
                    }
                }
            }
        }
    }
}

// ---------------------------------------------------------------------------
// tok transpose: tok[b*516+t][l] = (t<512 ? x_enc[b][l][t] : x_mark[b][l][t-512])
// split into bf16 hi/lo planes.
// ---------------------------------------------------------------------------
__global__ __launch_bounds__(256)
void tok_k(const float* __restrict__ xe, const float* __restrict__ xm,
           uint16_t* __restrict__ th, uint16_t* __restrict__ tl)
{
    const int b = blockIdx.z;
    const int t0 = blockIdx.x*32, l0 = blockIdx.y*32;
    __shared__ float tile[32][33];
    const int i = threadIdx.x >> 3;
    const int j4 = (threadIdx.x & 7) * 4;
#pragma unroll
    for (int c=0;c<4;c++){
        int t = t0 + j4 + c;
        float v = 0.0f;
        if (t < 512)      v = xe[((size_t)b*LL + l0+i)*NN + t];
        else if (t < 516) v = xm[((size_t)b*LL + l0+i)*4 + (t-512)];
        tile[i][j4+c] = v;
    }
    __syncthreads();
    int t = t0 + i;
    if (t < TT){
#pragma unroll
        for (int c=0;c<4;c++){
            uint16_t hi, lo; split_bf(tile[j4+c][i], hi, lo);
            size_t idx = ((size_t)b*TT + t)*512 + l0 + j4 + c;
            th[idx] = hi; tl[idx] = lo;
        }
    }
}

// ---------------------------------------------------------------------------
// weight transpose-split: src [z][K][N] fp32 -> dst [z(zstride)][N][K] bf16 hi/lo
// ---------------------------------------------------------------------------
__global__ __launch_bounds__(256)
void wtr_k(const float* __restrict__ src, uint16_t* __restrict__ dh,
           uint16_t* __restrict__ dl, int Ksz, int Nsz, size_t zstride)
{
    const int z = blockIdx.z;
    src += (size_t)z*Ksz*Nsz; dh += (size_t)z*zstride; dl += (size_t)z*zstride;
    __shared__ float tile[32][33];
    const int kt = blockIdx.y*32, nt = blockIdx.x*32;
    const int i = threadIdx.x >> 3;
    const int j4 = (threadIdx.x & 7) * 4;
#pragma unroll
    for (int c=0;c<4;c++){
        int n = nt + j4 + c;
        tile[i][j4+c] = (n < Nsz) ? src[(size_t)(kt+i)*Nsz + n] : 0.0f;
    }
    __syncthreads();
    int n = nt + i;
    if (n < Nsz){
#pragma unroll
        for (int c=0;c<4;c++){
            uint16_t hi, lo; split_bf(tile[j4+c][i], hi, lo);
            size_t idx = (size_t)n*Ksz + kt + j4 + c;
            dh[idx] = hi; dl[idx] = lo;
        }
    }
}

__global__ void catb_k(const float* __restrict__ bq, const float* __restrict__ bk,
                       const float* __restrict__ bv, float* __restrict__ dst){
    int j = blockIdx.x*256 + threadIdx.x;
    if (j >= 3072) return;
    int layer = j / 1536, r = j - layer*1536;
    float v;
    if (r < 512)       v = bq[layer*512 + r];
    else if (r < 1024) v = bk[layer*512 + r - 512];
    else               v = bv[layer*512 + r - 1024];
    dst[j] = v;
}

// ---------------------------------------------------------------------------
// Flash-style fp32 attention (unchanged math); writes SPLIT bf16 output.
// ---------------------------------------------------------------------------
__global__ __launch_bounds__(256)
void attn_k(const float* __restrict__ q, const float* __restrict__ k,
            const float* __restrict__ v, uint16_t* __restrict__ oh,
            uint16_t* __restrict__ ol)
{
    const int tt = blockIdx.x;
    const int h  = blockIdx.y;
    const int b  = blockIdx.z;
    const int t0 = tt * 64;
    const int tid = threadIdx.x;
    const int ty = tid >> 4, tx = tid & 15;
    const int ty4 = ty*4, tx4 = tx*4;

    __shared__ float QT[64][68];
    __shared__ float KT[64][68];
    __shared__ float Vs[64][68];
    __shared__ float PT[64][68];

    {
        int r  = tid >> 2;
        int dc = (tid & 3) * 16;
        int t  = t0 + r;
#pragma unroll
        for (int c=0;c<4;c++){
            float4 val;
            if (t < TT) val = *(const float4*)(q + ((size_t)(b*TT + t))*DD + h*DHD + dc + 4*c);
            else { val.x=val.y=val.z=val.w=0.0f; }
            QT[dc+4*c+0][r] = val.x; QT[dc+4*c+1][r] = val.y;
            QT[dc+4*c+2][r] = val.z; QT[dc+4*c+3][r] = val.w;
        }
    }

    float accO[4][4];
    float mrow[4], lrow[4];
#pragma unroll
    for (int i=0;i<4;i++){
        mrow[i] = -1e30f; lrow[i] = 0.0f;
#pragma unroll
        for (int j=0;j<4;j++) accO[i][j] = 0.0f;
    }
    const float scale = 0.125f;

    for (int st=0; st<9; st++){
        int s0 = st*64;
        __syncthreads();
        {
            int r  = tid >> 2;
            int dc = (tid & 3) * 16;
            int s  = s0 + r;
#pragma unroll
            for (int c=0;c<4;c++){
                float4 kv, vv;
                if (s < TT){
                    kv = *(const float4*)(k + ((size_t)(b*TT + s))*DD + h*DHD + dc + 4*c);
                    vv = *(const float4*)(v + ((size_t)(b*TT + s))*DD + h*DHD + dc + 4*c);
                } else { kv.x=kv.y=kv.z=kv.w=0.0f; vv.x=vv.y=vv.z=vv.w=0.0f; }
                KT[dc+4*c+0][r] = kv.x; KT[dc+4*c+1][r] = kv.y;
                KT[dc+4*c+2][r] = kv.z; KT[dc+4*c+3][r] = kv.w;
                *(float4*)&Vs[r][dc+4*c] = vv;
            }
        }
        __syncthreads();
        float sacc[4][4];
#pragma unroll
        for (int i=0;i<4;i++)
#pragma unroll
            for (int j=0;j<4;j++) sacc[i][j] = 0.0f;
#pragma unroll 8
        for (int d=0; d<64; d++){
            float4 av = *(const float4*)&QT[d][ty4];
            float4 bv = *(const float4*)&KT[d][tx4];
            float a[4] = {av.x, av.y, av.z, av.w};
            float bb2[4] = {bv.x, bv.y, bv.z, bv.w};
#pragma unroll
            for (int i=0;i<4;i++)
#pragma unroll
                for (int j=0;j<4;j++)
                    sacc[i][j] = fmaf(a[i], bb2[j], sacc[i][j]);
        }
        float p[4][4];
#pragma unroll
        for (int i=0;i<4;i++){
            float mx = -1e30f;
#pragma unroll
            for (int j=0;j<4;j++){
                float sv = sacc[i][j]*scale;
                if (s0 + tx4 + j >= TT) sv = -1e30f;
                p[i][j] = sv;
                mx = fmaxf(mx, sv);
            }
#pragma unroll
            for (int msk=1; msk<16; msk<<=1) mx = fmaxf(mx, __shfl_xor(mx, msk));
            float mnew  = fmaxf(mrow[i], mx);
            float alpha = __expf(mrow[i] - mnew);
            mrow[i] = mnew;
            float rs = 0.0f;
#pragma unroll
            for (int j=0;j<4;j++){
                float e = __expf(p[i][j] - mnew);
                p[i][j] = e;
                rs += e;
            }
#pragma unroll
            for (int msk=1; msk<16; msk<<=1) rs += __shfl_xor(rs, msk);
            lrow[i] = lrow[i]*alpha + rs;
#pragma unroll
            for (int j=0;j<4;j++) accO[i][j] *= alpha;
        }
#pragma unroll
        for (int j=0;j<4;j++)
#pragma unroll
            for (int i=0;i<4;i++)
                PT[tx4+j][ty4+i] = p[i][j];
        __syncthreads();
#pragma unroll 8
        for (int s=0; s<64; s++){
            float4 pa = *(const float4*)&PT[s][ty4];
            float4 vb = *(const float4*)&Vs[s][tx4];
            float a[4] = {pa.x, pa.y, pa.z, pa.w};
            float bb2[4] = {vb.x, vb.y, vb.z, vb.w};
#pragma unroll
            for (int i=0;i<4;i++)
#pragma unroll
                for (int j=0;j<4;j++)
                    accO[i][j] = fmaf(a[i], bb2[j], accO[i][j]);
        }
    }
#pragma unroll
    for (int i=0;i<4;i++){
        int t = t0 + ty4 + i;
        if (t < TT){
            float inv = 1.0f/lrow[i];
            size_t base = ((size_t)(b*TT + t))*DD + h*DHD + tx4;
#pragma unroll
            for (int j=0;j<4;j++){
                uint16_t hi, lo; split_bf(accO[i][j]*inv, hi, lo);
                oh[base + j] = hi; ol[base + j] = lo;
            }
        }
    }
}

// ---------------------------------------------------------------------------
// Residual + LayerNorm; writes fp32 + split-bf16 planes.
// ---------------------------------------------------------------------------
__global__ __launch_bounds__(256)
void ln_k(const float* __restrict__ src, const float* __restrict__ res,
          const float* __restrict__ w, const float* __restrict__ bia,
          float* __restrict__ dst, uint16_t* __restrict__ dbh,
          uint16_t* __restrict__ dbl)
{
    const int r = blockIdx.x;
    const int tid = threadIdx.x;
    const float* sp = src + (size_t)r*DD;
    float x0 = sp[tid], x1 = sp[tid + 256];
    if (res){
        x0 += res[(size_t)r*DD + tid];
        x1 += res[(size_t)r*DD + tid + 256];
    }
    float s  = x0 + x1;
    float sq = x0*x0 + x1*x1;
#pragma unroll
    for (int msk=1; msk<64; msk<<=1){
        s  += __shfl_xor(s,  msk);
        sq += __shfl_xor(sq, msk);
    }
    __shared__ float sm[8];
    int wv = tid >> 6, ln = tid & 63;
    if (ln == 0){ sm[wv] = s; sm[wv+4] = sq; }
    __syncthreads();
    s  = sm[0]+sm[1]+sm[2]+sm[3];
    sq = sm[4]+sm[5]+sm[6]+sm[7];
    float mu  = s * (1.0f/512.0f);
    float var = sq * (1.0f/512.0f) - mu*mu;
    float rsd = rsqrtf(var + 1e-5f);
    float y0 = (x0 - mu)*rsd*w[tid]       + bia[tid];
    float y1 = (x1 - mu)*rsd*w[tid + 256] + bia[tid + 256];
    dst[(size_t)r*DD + tid]       = y0;
    dst[(size_t)r*DD + tid + 256] = y1;
    uint16_t hi, lo;
    split_bf(y0, hi, lo); dbh[(size_t)r*DD + tid] = hi;       dbl[(size_t)r*DD + tid] = lo;
    split_bf(y1, hi, lo); dbh[(size_t)r*DD + tid + 256] = hi; dbl[(size_t)r*DD + tid + 256] = lo;
}

// ---------------------------------------------------------------------------
// memory-bank sims (fp32, deterministic split-K), top-K, fusion — unchanged
// ---------------------------------------------------------------------------
__global__ __launch_bounds__(256)
void simspart_k(const float* __restrict__ pred, const float* __restrict__ bank,
                float* __restrict__ dotp, float* __restrict__ nrmp)
{
    const int jt = blockIdx.x, kt = blockIdx.y;
    const int tid = threadIdx.x;
    const int jj = tid >> 4, qq = tid & 15;
    const int j  = jt*16 + jj;
    __shared__ float BS[16][68], PS[16][68];
    float dot = 0.0f, nr = 0.0f;
    const int e0base = kt * 10752;
    for (int eo=0; eo<10752; eo+=64){
        __syncthreads();
        {
            int rr = tid >> 4;
            int e4 = (tid & 15) * 4;
            int jr = jt*16 + rr;
            const float* bp = (jr < MM) ? (bank + (size_t)jr*PN)
                                        : (pred + (size_t)(jr - MM)*PN);
            *(float4*)&BS[rr][e4] = *(const float4*)(bp + e0base + eo + e4);
            *(float4*)&PS[rr][e4] = *(const float4*)(pred + (size_t)rr*PN + e0base + eo + e4);
        }
        __syncthreads();
#pragma unroll 16
        for (int e=0;e<64;e++){
            float bv = BS[jj][e];
            float pv = PS[qq][e];
            dot = fmaf(bv, pv, dot);
            nr  = fmaf(bv, bv, nr);
        }
    }
    dotp[((size_t)kt*528 + j)*16 + qq] = dot;
    if (qq == 0) nrmp[kt*528 + j] = nr;
}

__global__ void norms_k(const float* __restrict__ nrmp, float* __restrict__ invn){
    int j = blockIdx.x*blockDim.x + threadIdx.x;
    if (j < 528){
        float s = 0.0f;
        for (int kt=0; kt<16; kt++) s += nrmp[kt*528 + j];
        invn[j] = 1.0f/(sqrtf(s) + 1e-8f);
    }
}

__global__ void simsfin_k(const float* __restrict__ dotp, const float* __restrict__ invn,
                          float* __restrict__ sims){
    int fid = blockIdx.x*256 + threadIdx.x;
    int j = fid >> 4, q = fid & 15;
    float s = 0.0f;
    for (int kt=0; kt<16; kt++) s += dotp[((size_t)kt*528 + j)*16 + q];
    sims[q*528 + j] = s * invn[j] * invn[MM + q];
}

__global__ __launch_bounds__(64)
void topk_k(const float* __restrict__ sims, int* __restrict__ idx){
    const int q = blockIdx.x;
    const int lane = threadIdx.x;
    __shared__ float vals[528];
    for (int j=lane; j<528; j+=64) vals[j] = sims[q*528 + j];
    __syncthreads();
    for (int kk=0; kk<KNN; kk++){
        float bv = -3.0e38f; int bi = 1<<30;
        for (int j=lane; j<528; j+=64){
            float v2 = vals[j];
            if (v2 > bv || (v2 == bv && j < bi)){ bv = v2; bi = j; }
        }
#pragma unroll
        for (int msk=1; msk<64; msk<<=1){
            float ov = __shfl_xor(bv, msk);
            int   oi = __shfl_xor(bi, msk);
            if (ov > bv || (ov == bv && oi < bi)){ bv = ov; bi = oi; }
        }
        if (lane == 0){
            idx[q*KNN + kk] = bi;
            vals[bi] = -3.0e38f;
        }
        __syncthreads();
    }
}

__global__ __launch_bounds__(256)
void fuse_k(const float* __restrict__ pred, const float* __restrict__ bank,
            const int* __restrict__ idx, float* __restrict__ out){
    int u = blockIdx.x*256 + threadIdx.x;
    int b = u / (PN/4);
    int e = (u - b*(PN/4)) * 4;
    int id[KNN];
#pragma unroll
    for (int k2=0;k2<KNN;k2++) id[k2] = idx[b*KNN + k2];
    float4 pv = *(const float4*)(pred + (size_t)b*PN + e);
    float ax = 0.5f*pv.x, ay = 0.5f*pv.y, az = 0.5f*pv.z, aw = 0.5f*pv.w;
#pragma unroll
    for (int k2=0;k2<KNN;k2++){
        const float* rp = (id[k2] < MM) ? (bank + (size_t)id[k2]*PN)
                                        : (pred + (size_t)(id[k2]-MM)*PN);
        float4 rv = *(const float4*)(rp + e);
        ax = fmaf(0.05f, rv.x, ax); ay = fmaf(0.05f, rv.y, ay);
        az = fmaf(0.05f, rv.z, az); aw = fmaf(0.05f, rv.w, aw);
    }
    float4 ov; ov.x=ax; ov.y=ay; ov.z=az; ov.w=aw;
    *(float4*)(out + (size_t)b*PN + e) = ov;
}

// ---------------------------------------------------------------------------
extern "C" void kernel_launch(void* const* d_in, const int* in_sizes, int n_in,
                              void* d_out, int out_size, void* d_ws, size_t ws_size,
                              hipStream_t stream)
{
    (void)in_sizes; (void)n_in; (void)out_size; (void)ws_size;
    const float* x_enc  = (const float*)d_in[0];
    const float* x_mark = (const float*)d_in[1];
    const float* W_emb  = (const float*)d_in[4];
    const float* b_emb  = (const float*)d_in[5];
    const float* Wq  = (const float*)d_in[6];
    const float* Wk  = (const float*)d_in[7];
    const float* Wv  = (const float*)d_in[8];
    const float* Wo  = (const float*)d_in[9];
    const float* bq  = (const float*)d_in[10];
    const float* bk  = (const float*)d_in[11];
    const float* bv_ = (const float*)d_in[12];
    const float* bo  = (const float*)d_in[13];
    const float* ln1w = (const float*)d_in[14];
    const float* ln1b = (const float*)d_in[15];
    const float* ln2w = (const float*)d_in[16];
    const float* ln2b = (const float*)d_in[17];
    const float* Wff1 = (const float*)d_in[18];
    const float* bff1 = (const float*)d_in[19];
    const float* Wff2 = (const float*)d_in[20];
    const float* bff2 = (const float*)d_in[21];
    const float* lnfw = (const float*)d_in[22];
    const float* lnfb = (const float*)d_in[23];
    const float* Wproj = (const float*)d_in[24];
    const float* bproj = (const float*)d_in[25];
    const float* bank  = (const float*)d_in[26];
    float* out = (float*)d_out;

    char* pp = (char*)d_ws;
    auto a16 = [&](size_t elems)->uint16_t*{ uint16_t* r=(uint16_t*)pp; pp += ((elems*2 + 255)/256)*256; return r; };
    auto af  = [&](size_t elems)->float*  { float* r=(float*)pp;  pp += ((elems*4 + 255)/256)*256; return r; };

    uint16_t* wembT_h = a16(262144);        uint16_t* wembT_l = a16(262144);
    uint16_t* wqkvT_h = a16(2*1536*512);    uint16_t* wqkvT_l = a16(2*1536*512);
    uint16_t* woT_h   = a16(2*262144);      uint16_t* woT_l   = a16(2*262144);
    uint16_t* wff1T_h = a16(2*2048*512);    uint16_t* wff1T_l = a16(2*2048*512);
    uint16_t* wff2T_h = a16(2*512*2048);    uint16_t* wff2T_l = a16(2*512*2048);
    uint16_t* wprjT_h = a16(172032);        uint16_t* wprjT_l = a16(172032);
    float*    bqkv    = af(3072);
    uint16_t* hb_h    = a16((size_t)BT*512);
    uint16_t* hb_l    = a16((size_t)BT*512);
    uint16_t* tok_h   = a16((size_t)BT*512);     // og fp32 aliases tok region
    uint16_t* tok_l   = a16((size_t)BT*512);
    float*    og      = (float*)tok_h;
    float*    qb      = af((size_t)BT*512);
    float*    kb      = af((size_t)BT*512);
    float*    vb      = af((size_t)BT*512);
    uint16_t* t1b_h   = a16((size_t)BT*512);
    uint16_t* t1b_l   = a16((size_t)BT*512);
    uint16_t* midb_h  = (uint16_t*)qb;           // mid aliases qb..t1b (67.6 MB)
    uint16_t* midb_l  = midb_h + (size_t)BT*2048;
    float*    h       = af((size_t)BT*512);
    float*    pred    = af((size_t)BB*PN);
    float*    dotp    = af(16*528*16);
    float*    nrmp    = af(528*16);
    float*    invn    = af(528);
    float*    sims    = af(16*528);
    int*      idxp    = (int*)af(256);

    dim3 blk(256);

    // ---- input/weight prep ----
    tok_k<<<dim3(17,16,BB), blk, 0, stream>>>(x_enc, x_mark, tok_h, tok_l);
    wtr_k<<<dim3(16,16,1), blk, 0, stream>>>(W_emb, wembT_h, wembT_l, 512, 512, 262144);
    wtr_k<<<dim3(16,16,2), blk, 0, stream>>>(Wq, wqkvT_h,          wqkvT_l,          512, 512, 786432);
    wtr_k<<<dim3(16,16,2), blk, 0, stream>>>(Wk, wqkvT_h + 262144, wqkvT_l + 262144, 512, 512, 786432);
    wtr_k<<<dim3(16,16,2), blk, 0, stream>>>(Wv, wqkvT_h + 524288, wqkvT_l + 524288, 512, 512, 786432);
    wtr_k<<<dim3(16,16,2), blk, 0, stream>>>(Wo, woT_h, woT_l, 512, 512, 262144);
    wtr_k<<<dim3(64,16,2), blk, 0, stream>>>(Wff1, wff1T_h, wff1T_l, 512, 2048, 1048576);
    wtr_k<<<dim3(16,64,2), blk, 0, stream>>>(Wff2, wff2T_h, wff2T_l, 2048, 512, 1048576);
    wtr_k<<<dim3(11,16,1), blk, 0, stream>>>(Wproj, wprjT_h, wprjT_l, 512, 336, 172032);
    catb_k<<<dim3(12), blk, 0, stream>>>(bq, bk, bv_, bqkv);

    // ---- embedding GEMM ----
    bgemm<64, EPI_F32|EPI_BF16><<<dim3(8,65), blk, 0, stream>>>(
        tok_h, tok_l, wembT_h, wembT_l, b_emb, h, hb_h, hb_l, BT, 512, 512);

    for (int i=0;i<2;i++){
        bgemm<128, EPI_QKV><<<dim3(12,65), blk, 0, stream>>>(
            hb_h, hb_l, wqkvT_h + (size_t)i*786432, wqkvT_l + (size_t)i*786432,
            bqkv + i*1536, qb, nullptr, nullptr, BT, 1536, 512);
        attn_k<<<dim3(9,HH,BB), blk, 0, stream>>>(qb, kb, vb, t1b_h, t1b_l);
        bgemm<64, EPI_F32><<<dim3(8,65), blk, 0, stream>>>(
            t1b_h, t1b_l, woT_h + (size_t)i*262144, woT_l + (size_t)i*262144,
            bo + i*512, og, nullptr, nullptr, BT, 512, 512);
        ln_k<<<BT, blk, 0, stream>>>(h, og, ln1w + i*512, ln1b + i*512, h, hb_h, hb_l);
        bgemm<128, EPI_GELU|EPI_BF16><<<dim3(16,65), blk, 0, stream>>>(
            hb_h, hb_l, wff1T_h + (size_t)i*1048576, wff1T_l + (size_t)i*1048576,
            bff1 + i*DFFN, nullptr, midb_h, midb_l, BT, DFFN, 512);
        bgemm<64, EPI_F32><<<dim3(8,65), blk, 0, stream>>>(
            midb_h, midb_l, wff2T_h + (size_t)i*1048576, wff2T_l + (size_t)i*1048576,
            bff2 + i*512, og, nullptr, nullptr, BT, 512, DFFN);
        ln_k<<<BT, blk, 0, stream>>>(h, og, ln2w + i*512, ln2b + i*512, h, hb_h, hb_l);
    }

    ln_k<<<BT, blk, 0, stream>>>(h, nullptr, lnfw, lnfb, h, hb_h, hb_l);

    bgemm<64, EPI_PREDT><<<dim3(6,65), blk, 0, stream>>>(
        hb_h, hb_l, wprjT_h, wprjT_l, bproj, pred, nullptr, nullptr, BT, PP, 512);

    simspart_k<<<dim3(33,16), blk, 0, stream>>>(pred, bank, dotp, nrmp);
    norms_k<<<dim3(3), blk, 0, stream>>>(nrmp, invn);
    simsfin_k<<<dim3(33), blk, 0, stream>>>(dotp, invn, sims);
    topk_k<<<dim3(BB), dim3(64), 0, stream>>>(sims, idxp);
    fuse_k<<<dim3((BB*PN/4)/256), blk, 0, stream>>>(pred, bank, idxp, out);
}